// Round 9
// baseline (673.370 us; speedup 1.0000x reference)
//
#include <hip/hip_runtime.h>
#include <math.h>

#define B_GRAPHS 50
#define NPG0     2000
#define EPG      12000
#define F_IN_C   256
#define NHID     128
#define N0       (B_GRAPHS * NPG0)   // 100000
#define NE       (B_GRAPHS * EPG)    // 600000
#define RSEG     16                  // readout segments per graph
#define GSLOTS   7                   // ceil(50 graphs / 8 XCDs)
#define CPAD     136

typedef _Float16 f16x8 __attribute__((ext_vector_type(8)));
typedef float    f32x4 __attribute__((ext_vector_type(4)));

static inline int cdiv(int a, int b) { return (a + b - 1) / b; }

// ---------------- startup fill: zero cnt (N0) + accum ----------------
__global__ void k_fill_start(int* __restrict__ cnt, float* __restrict__ accum) {
    int i = blockIdx.x * 256 + threadIdx.x;
    if (i < N0) cnt[i] = 0;
    if (i < B_GRAPHS * 256) accum[i] = 0.f;
}

// ---------------- edge init + degree count (cnt pre-zeroed) ----------------
__global__ void k_init_edges(const int* __restrict__ ei, int* __restrict__ esrc,
                             int* __restrict__ edst, float* __restrict__ ew,
                             int* __restrict__ cnt) {
    int e = blockIdx.x * 256 + threadIdx.x;
    if (e < NE) {
        int d = ei[NE + e];
        esrc[e] = ei[e]; edst[e] = d; ew[e] = 1.0f;
        atomicAdd(&cnt[d], 1);
    }
}

// ---------------- all three weight transposes in one launch ----------------
__global__ void k_cvt_all(const float* __restrict__ W1, const float* __restrict__ W2,
                          const float* __restrict__ W3, _Float16* __restrict__ WT1,
                          _Float16* __restrict__ WT2, _Float16* __restrict__ WT3) {
    int t = blockIdx.x * 256 + threadIdx.x;   // grid exactly 65536
    if (t < 128 * 256) {
        int n = t >> 8, kk = t & 255;
        WT1[t] = (_Float16)W1[kk * 128 + n];
    } else if (t < 128 * 256 + 128 * 128) {
        int u = t - 32768; int n = u >> 7, kk = u & 127;
        WT2[u] = (_Float16)W2[kk * 128 + n];
    } else {
        int u = t - 49152; int n = u >> 7, kk = u & 127;
        WT3[u] = (_Float16)W3[kk * 128 + n];
    }
}

// ---------------- MFMA GEMM, weights read straight from L1/L2 (no W-LDS, no barriers) ----
// 128 rows x 128 cols per block, 4 waves. B fragments load per-lane from the hot 64/32 KB
// W^T region (L1/L2 resident). Per-wave PRIVATE epilogue LDS -> zero __syncthreads.
// GATHER: A row r comes from Xin[perm[r]] scaled by gate[r] (pool fused into GEMM).
template<int FP32IN, int F, int GATHER>
__global__ __launch_bounds__(256) void k_gemm_gb(const void* __restrict__ Xin,
                                                 const _Float16* __restrict__ WT,
                                                 const int* __restrict__ perm,
                                                 const float* __restrict__ gate,
                                                 _Float16* __restrict__ H, int N) {
    __shared__ _Float16 smem[4 * 32 * CPAD];   // per-wave private staging (34.8 KB)
    const int tid  = threadIdx.x;
    const int wave = tid >> 6, lane = tid & 63;
    const int quad = lane >> 4, l16 = lane & 15;
    const int m_blk = blockIdx.x * 128;

    f32x4 acc[2][8];
#pragma unroll
    for (int i = 0; i < 2; ++i)
#pragma unroll
        for (int j = 0; j < 8; ++j) acc[i][j] = {0.f, 0.f, 0.f, 0.f};

    int row0 = m_blk + wave * 32 + l16;
    int row1 = row0 + 16;
    if (row0 > N - 1) row0 = N - 1;
    if (row1 > N - 1) row1 = N - 1;
    _Float16 g0 = (_Float16)1.0f, g1 = (_Float16)1.0f;
    if (GATHER) {
        g0 = (_Float16)gate[row0]; g1 = (_Float16)gate[row1];
        row0 = perm[row0]; row1 = perm[row1];
    }
    constexpr int NKQ = F / 32;
    const _Float16* WTb = WT + l16 * F + quad * 8;   // B-frag base for this lane

    if (FP32IN) {
        constexpr int PD = 2;
        const float* base0 = (const float*)Xin + (size_t)row0 * F + quad * 8;
        const float* base1 = (const float*)Xin + (size_t)row1 * F + quad * 8;
        float4 p0[PD][2], p1[PD][2];
#pragma unroll
        for (int i = 0; i < PD; ++i) {
            p0[i][0] = ((const float4*)(base0 + i * 32))[0];
            p0[i][1] = ((const float4*)(base0 + i * 32))[1];
            p1[i][0] = ((const float4*)(base1 + i * 32))[0];
            p1[i][1] = ((const float4*)(base1 + i * 32))[1];
        }
#pragma unroll
        for (int kq = 0; kq < NKQ; ++kq) {
            const int b = kq % PD;
            float4 f0 = p0[b][0], f1 = p0[b][1], h0 = p1[b][0], h1 = p1[b][1];
            if (kq + PD < NKQ) {
                p0[b][0] = ((const float4*)(base0 + (kq + PD) * 32))[0];
                p0[b][1] = ((const float4*)(base0 + (kq + PD) * 32))[1];
                p1[b][0] = ((const float4*)(base1 + (kq + PD) * 32))[0];
                p1[b][1] = ((const float4*)(base1 + (kq + PD) * 32))[1];
            }
            f16x8 af0 = (f16x8){(_Float16)f0.x,(_Float16)f0.y,(_Float16)f0.z,(_Float16)f0.w,
                                (_Float16)f1.x,(_Float16)f1.y,(_Float16)f1.z,(_Float16)f1.w};
            f16x8 af1 = (f16x8){(_Float16)h0.x,(_Float16)h0.y,(_Float16)h0.z,(_Float16)h0.w,
                                (_Float16)h1.x,(_Float16)h1.y,(_Float16)h1.z,(_Float16)h1.w};
            f16x8 bf[8];
#pragma unroll
            for (int j = 0; j < 8; ++j)
                bf[j] = *(const f16x8*)&WTb[j * 16 * F + kq * 32];
#pragma unroll
            for (int j = 0; j < 8; ++j) {
                acc[0][j] = __builtin_amdgcn_mfma_f32_16x16x32_f16(af0, bf[j], acc[0][j], 0, 0, 0);
                acc[1][j] = __builtin_amdgcn_mfma_f32_16x16x32_f16(af1, bf[j], acc[1][j], 0, 0, 0);
            }
        }
    } else {
        // F=128: full prefetch — all 2*NKQ A-loads issued before any MFMA
        const _Float16* base0 = (const _Float16*)Xin + (size_t)row0 * F + quad * 8;
        const _Float16* base1 = (const _Float16*)Xin + (size_t)row1 * F + quad * 8;
        f16x8 q0[NKQ], q1[NKQ];
#pragma unroll
        for (int i = 0; i < NKQ; ++i) {
            q0[i] = *(const f16x8*)(base0 + i * 32);
            q1[i] = *(const f16x8*)(base1 + i * 32);
        }
#pragma unroll
        for (int kq = 0; kq < NKQ; ++kq) {
            f16x8 af0 = q0[kq], af1 = q1[kq];
            if (GATHER) { af0 = af0 * g0; af1 = af1 * g1; }
            f16x8 bf[8];
#pragma unroll
            for (int j = 0; j < 8; ++j)
                bf[j] = *(const f16x8*)&WTb[j * 16 * F + kq * 32];
#pragma unroll
            for (int j = 0; j < 8; ++j) {
                acc[0][j] = __builtin_amdgcn_mfma_f32_16x16x32_f16(af0, bf[j], acc[0][j], 0, 0, 0);
                acc[1][j] = __builtin_amdgcn_mfma_f32_16x16x32_f16(af1, bf[j], acc[1][j], 0, 0, 0);
            }
        }
    }

    // ---- epilogue: per-wave PRIVATE LDS bounce (no barriers) ----
    _Float16* sC = smem + wave * 32 * CPAD;   // [32][CPAD] private to this wave
#pragma unroll
    for (int i = 0; i < 2; ++i)
#pragma unroll
        for (int j = 0; j < 8; ++j)
#pragma unroll
            for (int g = 0; g < 4; ++g)
                sC[(i * 16 + quad * 4 + g) * CPAD + j * 16 + l16] = (_Float16)acc[i][j][g];
    {
        int rl = lane >> 1;                    // local row 0..31
        int gr = m_blk + wave * 32 + rl;
        if (gr < N) {
            _Float16* Hr = H + (size_t)gr * 128 + (lane & 1) * 64;
            const _Float16* Sr = sC + rl * CPAD + (lane & 1) * 64;
#pragma unroll
            for (int c = 0; c < 8; ++c)
                *(f16x8*)&Hr[c * 8] = *(const f16x8*)&Sr[c * 8];
        }
    }
}

// -------- merged CSR scan + fill: one 1024-thread block per graph, LDS cursors --------
__global__ __launch_bounds__(1024) void k_scan_csr(const int* __restrict__ cnt,
                                                   int* __restrict__ offs,
                                                   const int* __restrict__ esrc,
                                                   const int* __restrict__ edst,
                                                   const float* __restrict__ ew,
                                                   int* __restrict__ csr_src,
                                                   float* __restrict__ csr_norm, int npg) {
    __shared__ int ch[1024];
    __shared__ int lcur[2048];
    int b = blockIdx.x, tid = threadIdx.x;
    int base = b * npg;
    int s0 = tid * 2, s1 = s0 + 2;
    if (s1 > npg) s1 = npg; if (s0 > npg) s0 = npg;
    int s = 0;
    for (int i = s0; i < s1; ++i) s += cnt[base + i];
    ch[tid] = s;
    __syncthreads();
    for (int d = 1; d < 1024; d <<= 1) {
        int t = ch[tid] + ((tid >= d) ? ch[tid - d] : 0);
        __syncthreads();
        ch[tid] = t;
        __syncthreads();
    }
    int run = b * EPG + ch[tid] - s;
    for (int i = s0; i < s1; ++i) {
        offs[base + i] = run; lcur[i] = run;
        run += cnt[base + i];
    }
    __syncthreads();
    // edge pass for this graph's slice (edge slots stay within [b*EPG,(b+1)*EPG))
    for (int e = b * EPG + tid; e < (b + 1) * EPG; e += 1024) {
        if (ew[e] > 0.f) {
            int sN = esrc[e], d = edst[e];
            int pos = atomicAdd(&lcur[d - base], 1);
            csr_src[pos] = sN;
            csr_norm[pos] = rsqrtf((float)(cnt[sN] + 1)) * rsqrtf((float)(cnt[d] + 1));
        }
    }
}

// -------- aggregation + fused score projection, 8-edge pipeline + XCD swizzle --------
__global__ __launch_bounds__(256) void k_agg(const _Float16* __restrict__ H,
                                             const int* __restrict__ csr_src,
                                             const float* __restrict__ csr_norm,
                                             const int* __restrict__ offs,
                                             const int* __restrict__ cnt,
                                             const float* __restrict__ bias,
                                             const float* __restrict__ Ws,
                                             _Float16* __restrict__ X,
                                             float* __restrict__ hs,
                                             int bpg, int npg) {
    int bi = blockIdx.x;
    int x = bi & 7, s = bi >> 3;
    int gslot = s / bpg, blk = s - gslot * bpg;
    int g = x + 8 * gslot;
    if (g >= B_GRAPHS) return;
    int node = g * npg + blk * 4 + (threadIdx.x >> 6);
    int lane = threadIdx.x & 63;
    int quad = lane >> 4, l16 = lane & 15;

    int st = offs[node], c = cnt[node], en = st + c;
    float acc[8];
#pragma unroll
    for (int j = 0; j < 8; ++j) acc[j] = 0.f;

    if (c > 0) {
        for (int e0 = st; e0 < en; e0 += 8) {
            int eA = e0 + quad, eB = eA + 4;
            int ecA = eA < en ? eA : en - 1;
            int ecB = eB < en ? eB : en - 1;
            int uA = csr_src[ecA], uB = csr_src[ecB];
            float nA = (eA < en) ? csr_norm[ecA] : 0.f;
            float nB = (eB < en) ? csr_norm[ecB] : 0.f;
            f16x8 hA = *(const f16x8*)&H[(size_t)uA * NHID + l16 * 8];
            f16x8 hB = *(const f16x8*)&H[(size_t)uB * NHID + l16 * 8];
#pragma unroll
            for (int j = 0; j < 8; ++j) acc[j] = fmaf((float)hA[j], nA, acc[j]);
#pragma unroll
            for (int j = 0; j < 8; ++j) acc[j] = fmaf((float)hB[j], nB, acc[j]);
        }
    }
#pragma unroll
    for (int j = 0; j < 8; ++j) {
        acc[j] += __shfl_xor(acc[j], 16, 64);
        acc[j] += __shfl_xor(acc[j], 32, 64);
    }
    float invd = 1.f / (float)(c + 1);
    f16x8 hn = *(const f16x8*)&H[(size_t)node * NHID + l16 * 8];
    float4 b0 = *(const float4*)&bias[l16 * 8];
    float4 b1 = *(const float4*)&bias[l16 * 8 + 4];
    float4 w0 = *(const float4*)&Ws[l16 * 8];
    float4 w1 = *(const float4*)&Ws[l16 * 8 + 4];
    const float bb[8] = {b0.x, b0.y, b0.z, b0.w, b1.x, b1.y, b1.z, b1.w};
    const float ww[8] = {w0.x, w0.y, w0.z, w0.w, w1.x, w1.y, w1.z, w1.w};
    float sd = 0.f;
    f16x8 o;
#pragma unroll
    for (int j = 0; j < 8; ++j) {
        float v = fmaxf(acc[j] + (float)hn[j] * invd + bb[j], 0.f);
        o[j] = (_Float16)v;
        sd = fmaf(v, ww[j], sd);
    }
    if (quad == 0)
        *(f16x8*)&X[(size_t)node * NHID + l16 * 8] = o;
    sd += __shfl_xor(sd, 1, 64);
    sd += __shfl_xor(sd, 2, 64);
    sd += __shfl_xor(sd, 4, 64);
    sd += __shfl_xor(sd, 8, 64);
    if (lane == 0) hs[node] = sd;
}

// ------- per-graph: fused score GCN + top-k bitonic sort (desc score, asc idx) -------
// Also fills mapping for ALL nodes and zeroes next layer's cnt.
__global__ __launch_bounds__(1024) void k_topk(const float* __restrict__ hs,
                                               const int* __restrict__ csr_src,
                                               const float* __restrict__ csr_norm,
                                               const int* __restrict__ offs,
                                               const int* __restrict__ cnt,
                                               const float* __restrict__ bs,
                                               int* __restrict__ mapping,
                                               int* __restrict__ perm,
                                               float* __restrict__ gate,
                                               int* __restrict__ cntN,
                                               int npg, int k) {
    __shared__ float ss[2048];
    __shared__ int   si[2048];
    int b = blockIdx.x, tid = threadIdx.x;
    float bias0 = bs[0];
    for (int i = tid; i < 2048; i += 1024) {
        if (i < npg) {
            int node = b * npg + i;
            int st = offs[node], c = cnt[node];
            float a = 0.f;
            for (int e = st; e < st + c; ++e)
                a = fmaf(hs[csr_src[e]], csr_norm[e], a);
            ss[i] = a + hs[node] / (float)(c + 1) + bias0;
            si[i] = i;
        } else { ss[i] = -__builtin_inff(); si[i] = i; }
    }
    __syncthreads();
    for (int size = 2; size <= 2048; size <<= 1) {
        for (int stride = size >> 1; stride > 0; stride >>= 1) {
            int t = tid;
            int i = ((t & ~(stride - 1)) << 1) | (t & (stride - 1));
            int j = i | stride;
            float sa = ss[i], sb = ss[j];
            int   ia = si[i], ib = si[j];
            bool b_before_a = (sb > sa) || (sb == sa && ib < ia);
            bool forward = ((i & size) == 0);
            bool doswap = forward ? b_before_a : !b_before_a;
            if (doswap) { ss[i] = sb; ss[j] = sa; si[i] = ib; si[j] = ia; }
            __syncthreads();
        }
    }
    for (int j = tid; j < npg; j += 1024) {
        int oldg = b * npg + si[j];
        if (j < k) {
            int newg = b * k + j;
            perm[newg] = oldg;
            mapping[oldg] = newg;
            gate[newg] = tanhf(ss[j]);
        } else {
            mapping[oldg] = -1;
        }
    }
    for (int j = tid; j < k; j += 1024) cntN[b * k + j] = 0;
}

// ---------------- partial readout over pooled rows (no XP materialization) ----------------
__global__ __launch_bounds__(128) void k_pool_readout(const _Float16* __restrict__ X,
                                                      const float* __restrict__ gate,
                                                      const int* __restrict__ perm,
                                                      float* __restrict__ pmax,
                                                      float* __restrict__ psum, int k) {
    int s = blockIdx.x, b = blockIdx.y, f = threadIdx.x;
    int j0 = (k * s) / RSEG, j1 = (k * (s + 1)) / RSEG;
    float mx = -__builtin_inff(), sm = 0.f;
    for (int j = j0; j < j1; ++j) {
        int g = b * k + j;
        int old = perm[g];
        float v = (float)X[(size_t)old * NHID + f] * gate[g];
        mx = fmaxf(mx, v);
        sm += v;
    }
    pmax[(size_t)(b * RSEG + s) * NHID + f] = mx;
    psum[(size_t)(b * RSEG + s) * NHID + f] = sm;
}

__global__ __launch_bounds__(128) void k_readout_comb(const float* __restrict__ pmax,
                                                      const float* __restrict__ psum,
                                                      float* __restrict__ accum, int k) {
    int b = blockIdx.x, f = threadIdx.x;
    float mx = -__builtin_inff(), sm = 0.f;
#pragma unroll
    for (int s = 0; s < RSEG; ++s) {
        mx = fmaxf(mx, pmax[(size_t)(b * RSEG + s) * NHID + f]);
        sm += psum[(size_t)(b * RSEG + s) * NHID + f];
    }
    accum[b * 256 + f]       += mx;
    accum[b * 256 + 128 + f] += sm / (float)k;
}

// ---------------- edge remap (in place) + next-layer degree count ----------------
__global__ void k_remap(int* __restrict__ esrc, int* __restrict__ edst,
                        float* __restrict__ ew, const int* __restrict__ mapping,
                        int* __restrict__ cntN) {
    int e = blockIdx.x * 256 + threadIdx.x;
    if (e >= NE) return;
    int sN = esrc[e], d = edst[e];
    float we = ew[e];
    int ns = mapping[sN], nd = mapping[d];
    bool valid = (ns >= 0) && (nd >= 0) && (we > 0.f);
    esrc[e] = valid ? ns : 0;
    edst[e] = valid ? nd : 0;
    ew[e] = valid ? we : 0.f;
    if (valid) atomicAdd(&cntN[nd], 1);
}

// ---------------- fused layer-3 readout-combine + final linear ----------------
__global__ __launch_bounds__(128) void k_comb_final(const float* __restrict__ pmax,
                                                    const float* __restrict__ psum,
                                                    const float* __restrict__ accum,
                                                    const float* __restrict__ Wl,
                                                    const float* __restrict__ bl,
                                                    float* __restrict__ out, int k) {
    __shared__ float a[256];
    int b = blockIdx.x, f = threadIdx.x;
    float mx = -__builtin_inff(), sm = 0.f;
#pragma unroll
    for (int s = 0; s < RSEG; ++s) {
        mx = fmaxf(mx, pmax[(size_t)(b * RSEG + s) * NHID + f]);
        sm += psum[(size_t)(b * RSEG + s) * NHID + f];
    }
    a[f]       = accum[b * 256 + f] + mx;
    a[128 + f] = accum[b * 256 + 128 + f] + sm / (float)k;
    __syncthreads();
    float s = bl[f];
    for (int i = 0; i < 256; ++i) s = fmaf(a[i], Wl[i * NHID + f], s);
    out[b * NHID + f] = fmaxf(s, 0.f);
}

extern "C" void kernel_launch(void* const* d_in, const int* in_sizes, int n_in,
                              void* d_out, int out_size, void* d_ws, size_t ws_size,
                              hipStream_t stream) {
    const float* x0 = (const float*)d_in[0];
    const float* Wm[3] = {(const float*)d_in[1], (const float*)d_in[5], (const float*)d_in[9]};
    const float* bm[3] = {(const float*)d_in[2], (const float*)d_in[6], (const float*)d_in[10]};
    const float* Wsc[3] = {(const float*)d_in[3], (const float*)d_in[7], (const float*)d_in[11]};
    const float* bsc[3] = {(const float*)d_in[4], (const float*)d_in[8], (const float*)d_in[12]};
    const float* Wl = (const float*)d_in[13];
    const float* bl = (const float*)d_in[14];
    const int*   ei = (const int*)d_in[15];
    float* out = (float*)d_out;

    _Float16* bufA = (_Float16*)d_ws;                       // N0*128 halves (H)
    _Float16* bufB = bufA + (size_t)N0 * NHID;              // N0*128 (X)
    _Float16* WT1  = bufB + (size_t)N0 * NHID;              // 128*256
    _Float16* WT2  = WT1 + 128 * 256;                       // 128*128
    _Float16* WT3  = WT2 + 128 * 128;                       // 128*128
    float* hs     = (float*)(WT3 + 128 * 128);              // N0
    float* gate   = hs + N0;                                // N0
    float* accum  = gate + N0;                              // B*256
    float* pmax   = accum + B_GRAPHS * 256;                 // B*RSEG*128
    float* psum   = pmax + B_GRAPHS * RSEG * NHID;          // B*RSEG*128
    int*   cntA   = (int*)(psum + B_GRAPHS * RSEG * NHID);  // N0
    int*   cntB   = cntA + N0;                              // N0
    int*   offs   = cntB + N0;                              // N0
    int*   mapping= offs + N0;                              // N0
    int*   perm   = mapping + N0;                           // N0
    int*   esrc   = perm + N0;                              // NE
    int*   edst   = esrc + NE;                              // NE
    float* ew     = (float*)(edst + NE);                    // NE
    int*   csr_src= (int*)(ew + NE);                        // NE
    float* csr_norm = (float*)(csr_src + NE);               // NE

    _Float16* WTs[3] = {WT1, WT2, WT3};
    const int EG = cdiv(NE, 256);

    k_fill_start<<<cdiv(N0, 256), 256, 0, stream>>>(cntA, accum);
    k_init_edges<<<EG, 256, 0, stream>>>(ei, esrc, edst, ew, cntA);
    k_cvt_all<<<256, 256, 0, stream>>>(Wm[0], Wm[1], Wm[2], WT1, WT2, WT3);

    int npg = NPG0;
    _Float16* Hbuf = bufA; _Float16* Xbuf = bufB;

    for (int layer = 0; layer < 3; ++layer) {
        int N = B_GRAPHS * npg;
        int k = (npg * 4) / 5;   // ceil(0.8*n) exact for 2000/1600/1280
        int bpg = npg >> 2;      // blocks per graph in k_agg
        int* cnt  = (layer == 1) ? cntB : cntA;
        int* cntN = (layer == 1) ? cntA : cntB;

        if (layer == 0)
            k_gemm_gb<1, 256, 0><<<cdiv(N, 128), 256, 0, stream>>>(x0, WTs[0], perm, gate, Hbuf, N);
        else
            k_gemm_gb<0, 128, 1><<<cdiv(N, 128), 256, 0, stream>>>(Xbuf, WTs[layer], perm, gate, Hbuf, N);
        k_scan_csr<<<B_GRAPHS, 1024, 0, stream>>>(cnt, offs, esrc, edst, ew, csr_src, csr_norm, npg);
        k_agg<<<8 * GSLOTS * bpg, 256, 0, stream>>>(Hbuf, csr_src, csr_norm, offs, cnt,
                                                    bm[layer], Wsc[layer], Xbuf, hs, bpg, npg);
        k_topk<<<B_GRAPHS, 1024, 0, stream>>>(hs, csr_src, csr_norm, offs, cnt, bsc[layer],
                                              mapping, perm, gate, cntN, npg, k);
        k_pool_readout<<<dim3(RSEG, B_GRAPHS), 128, 0, stream>>>(Xbuf, gate, perm, pmax, psum, k);
        if (layer < 2) {
            k_remap<<<EG, 256, 0, stream>>>(esrc, edst, ew, mapping, cntN);
            k_readout_comb<<<B_GRAPHS, 128, 0, stream>>>(pmax, psum, accum, k);
        } else {
            k_comb_final<<<B_GRAPHS, 128, 0, stream>>>(pmax, psum, accum, Wl, bl, out, k);
        }

        npg = k;
    }
}